// Round 7
// baseline (1129.305 us; speedup 1.0000x reference)
//
#include <hip/hip_runtime.h>
#include <cstdio>
#include <cstdint>

typedef unsigned int u32;
typedef unsigned short u16;
typedef short bf16x8 __attribute__((ext_vector_type(8)));   // 8 bf16 = 4 VGPRs (MFMA A/B operand)
typedef float f32x4 __attribute__((ext_vector_type(4)));    // MFMA C/D operand

#define NPTS 262144
#define CDIM 256
#define KCLS 20
#define NSTRIP 16384       // N/16 strips
#define LSLOT 256          // loss aggregation slots

// ---- workspace layout (bytes) ----
// [0, 134217728)       : h2 bf16, PRODUCER-NATIVE: [strip][ct 0..15][lane 0..63][4]
//                        lane (q,i16) holds rows strip*16 + q*4+{0..3}, ch ct*16+i16
// + 163840 reserved    : Wt3 bf16 [ct 0..17][kq 0..7][lane 0..63][8]  (frag-major,
//                        slab (ct,kq) = one 1KB gl_lds unit; 144 KB used)
// + 8192               : w2p f32 [256][4]  (x,y,z,0 per channel)
// + 524288             : aggBN  [256][512] f32 (s1[256] | s2[256] per block-slot)
// + 2048               : aggNLL [256][2]  f32 (nll, cnt) — plain stores now
// + 4096               : aggL   [256][4]  f32 (l1, cos, mask, pad) — atomics
// + 2048               : Aarr[256], Barr[256]
#define OFF_WT    ((size_t)134217728)
#define OFF_W2P   (OFF_WT + (size_t)163840)
#define OFF_AGGBN (OFF_W2P + (size_t)8192)
#define OFF_AGGNL (OFF_AGGBN + (size_t)524288)
#define OFF_AGGL  (OFF_AGGNL + (size_t)2048)
#define OFF_AB    (OFF_AGGL + (size_t)4096)
#define WS_NEED   (OFF_AB + (size_t)2048)
#define MEMSET_OFF OFF_AGGBN
#define MEMSET_LEN ((size_t)(524288 + 2048 + 4096))

__device__ __forceinline__ u16 bf16rne(float x) {
    u32 u = __float_as_uint(x);
    u32 r = u + 0x7FFFu + ((u >> 16) & 1u);   // round-to-nearest-even
    return (u16)(r >> 16);
}
__device__ __forceinline__ float bf2f(u16 b) {
    return __uint_as_float(((u32)b) << 16);
}

// ---------------------------------------------------------------------------
// kernel 0: build Wt3 frag-major bf16 (144 KB) + w2p f32 [256][4].
// Wt3 slab (ct,kq), lane (q,i16), elem e holds W[k=kq*32+q*8+e][n=ct*16+i16]
// where W = [w1 | ws | zero-pad] (288 cols). 256 blocks (k) x 288 threads (n).
// ---------------------------------------------------------------------------
__global__ void k_prep(const float* __restrict__ w1, const float* __restrict__ wsm,
                       const float* __restrict__ w2,
                       u16* __restrict__ Wt3, float* __restrict__ w2p) {
    int k = blockIdx.x;      // 0..255
    int n = threadIdx.x;     // 0..287
    float v = 0.f;
    if (n < 256) v = w1[k * 256 + n];
    else if (n < 256 + KCLS) v = wsm[k * KCLS + (n - 256)];
    int ct = n >> 4, i16 = n & 15;
    int kq = k >> 5, q = (k >> 3) & 3, e = k & 7;
    Wt3[(((size_t)(ct * 8 + kq) * 64) + (q * 16 + i16)) * 8 + e] = bf16rne(v);
    if (n < 4) w2p[k * 4 + n] = (n < 3) ? w2[k * 3 + n] : 0.f;
}

// ---------------------------------------------------------------------------
// kernel 1 (v9, B-STATIONARY FUSED): h = feat@w1(+b1), logits = feat@ws(+bs),
// NLL + BN partials, all in ONE pass with ONE barrier.
// 256 blocks x 1024 threads, 1 block/CU, 16 waves. Full W (144 KB frag-major)
// staged to LDS once (9 gl_lds/wave); after one __syncthreads each wave
// independently streams 4 strips of 16 rows: feat global->reg A-frags,
// ct-outer MFMA (acc live = 4 regs), h stored producer-native (coalesced,
// NO LDS transpose). BN via LDS f32 atomics -> plain per-block slot store.
// Rationale: 6 rounds showed the 4-chunk barriered skeleton pinned at
// ~155-185us regardless of schedule; this removes chunks, barriers (all but
// one), block turnover, transpose, and global atomics in one stroke.
// ---------------------------------------------------------------------------
__global__ __launch_bounds__(1024, 4) void k_fused(
    const float* __restrict__ feat, const float* __restrict__ b1,
    const float* __restrict__ bs, const int* __restrict__ segment,
    const u16* __restrict__ Wt3, u16* __restrict__ h2,
    float* __restrict__ aggBN, float* __restrict__ aggNLL)
{
    __shared__ u16 W[73728];          // 144 KB: [ct*8+kq][lane][8]
    __shared__ float bn[512];         // s1[256] | s2[256]
    __shared__ float nllw[2];

    const int t = threadIdx.x;
    const int lane = t & 63;
    const int wv = t >> 6;            // 0..15
    const int q = lane >> 4;
    const int i16 = lane & 15;

    if (t < 512) bn[t] = 0.f;
    if (t < 2) nllw[t] = 0.f;

    // ---- stage full W: wave wv stages slabs [wv*9, wv*9+9) (1 KB each) ----
#pragma unroll
    for (int j = 0; j < 9; ++j) {
        int slab = wv * 9 + j;        // 0..143
        const u16* src = Wt3 + (size_t)slab * 512 + lane * 8;
        __builtin_amdgcn_global_load_lds(
            (const __attribute__((address_space(1))) u32*)src,
            (__attribute__((address_space(3))) u32*)&W[slab * 512], 16, 0, 0);
    }
    __syncthreads();   // the ONE barrier: drains gl_lds + bn init visible

    const float bsv0 = bs[i16];
    const float bsv1 = (16 + i16 < KCLS) ? bs[16 + i16] : 0.f;
    float nllacc = 0.f, cntacc = 0.f;
    const f32x4 fz = {0.f, 0.f, 0.f, 0.f};

#pragma unroll 1
    for (int i = 0; i < 4; ++i) {
        const int s = blockIdx.x * 64 + i * 16 + wv;    // strip id
        // ---- feat A-frags: lane (q,i16) = row s*16+i16, k = kq*32+q*8.. ----
        const float* fb = feat + (size_t)(s * 16 + i16) * 256 + q * 8;
        float4 fA[8], fB[8];
#pragma unroll
        for (int kq = 0; kq < 8; ++kq) {
            fA[kq] = *(const float4*)(fb + kq * 32);
            fB[kq] = *(const float4*)(fb + kq * 32 + 4);
        }
        bf16x8 af[8];
#pragma unroll
        for (int kq = 0; kq < 8; ++kq) {
            bf16x8 f;
            ((u16*)&f)[0] = bf16rne(fA[kq].x); ((u16*)&f)[1] = bf16rne(fA[kq].y);
            ((u16*)&f)[2] = bf16rne(fA[kq].z); ((u16*)&f)[3] = bf16rne(fA[kq].w);
            ((u16*)&f)[4] = bf16rne(fB[kq].x); ((u16*)&f)[5] = bf16rne(fB[kq].y);
            ((u16*)&f)[6] = bf16rne(fB[kq].z); ((u16*)&f)[7] = bf16rne(fB[kq].w);
            af[kq] = f;
        }

        // ---- main cols: ct-outer, acc live = 1 tile ----
#pragma unroll
        for (int ct = 0; ct < 16; ++ct) {
            f32x4 a = fz;
#pragma unroll
            for (int kq = 0; kq < 8; ++kq)
                a = __builtin_amdgcn_mfma_f32_16x16x32_bf16(
                    af[kq], *(const bf16x8*)&W[((ct * 8 + kq) * 64 + lane) * 8], a, 0, 0, 0);
            float b1v = b1[ct * 16 + i16];
            float v0 = a[0] + b1v, v1 = a[1] + b1v, v2 = a[2] + b1v, v3 = a[3] + b1v;
            // h2 store: rows q*4+j, ch ct*16+i16 -> 8 B/lane, 512 B/wave-instr
            u32 d0 = (u32)bf16rne(v0) | ((u32)bf16rne(v1) << 16);
            u32 d1 = (u32)bf16rne(v2) | ((u32)bf16rne(v3) << 16);
            uint2 dd = {d0, d1};
            *(uint2*)((char*)h2 + (size_t)s * 8192 + ct * 512 + lane * 8) = dd;
            // BN partial: sum over this lane's 4 rows, then over q (xor 16,32)
            float s1 = v0 + v1 + v2 + v3;
            float s2 = fmaf(v0, v0, fmaf(v1, v1, fmaf(v2, v2, v3 * v3)));
            s1 += __shfl_xor(s1, 16); s1 += __shfl_xor(s1, 32);
            s2 += __shfl_xor(s2, 16); s2 += __shfl_xor(s2, 32);
            if (lane < 16) {
                atomicAdd(&bn[ct * 16 + lane], s1);
                atomicAdd(&bn[256 + ct * 16 + lane], s2);
            }
        }

        // ---- logits (ct 16,17) + NLL (proven lane mapping: col=i16, row=q*4+j) ----
        f32x4 l0 = fz, l1 = fz;
#pragma unroll
        for (int kq = 0; kq < 8; ++kq) {
            l0 = __builtin_amdgcn_mfma_f32_16x16x32_bf16(
                af[kq], *(const bf16x8*)&W[((16 * 8 + kq) * 64 + lane) * 8], l0, 0, 0, 0);
            l1 = __builtin_amdgcn_mfma_f32_16x16x32_bf16(
                af[kq], *(const bf16x8*)&W[((17 * 8 + kq) * 64 + lane) * 8], l1, 0, 0, 0);
        }
#pragma unroll
        for (int j = 0; j < 4; ++j) {
            int rowr = s * 16 + q * 4 + j;
            float a0 = l0[j] + bsv0;                        // classes 0..15
            float a1raw = l1[j] + bsv1;                     // classes 16..31 (<20 real)
            float a1m = (i16 < 4) ? a1raw : -3.0e38f;
            float mx = fmaxf(a0, a1m);
#pragma unroll
            for (int d = 1; d < 16; d <<= 1) mx = fmaxf(mx, __shfl_xor(mx, d));
            float se = __expf(a0 - mx) + ((i16 < 4) ? __expf(a1raw - mx) : 0.f);
#pragma unroll
            for (int d = 1; d < 16; d <<= 1) se += __shfl_xor(se, d);
            int tg = segment[rowr];
            float v0 = __shfl(a0, (lane & 48) + (tg & 15));
            float v1 = __shfl(a1raw, (lane & 48) + ((tg - 16) & 15));
            float lt = (tg < 16) ? v0 : v1;
            if (i16 == 0 && tg >= 0) {                      // ignore_index = -1
                nllacc += __logf(se) + mx - lt;
                cntacc += 1.f;
            }
        }
    }

    // ---- NLL wave reduce -> LDS, then per-block plain stores ----
#pragma unroll
    for (int d = 1; d < 64; d <<= 1) {
        nllacc += __shfl_xor(nllacc, d);
        cntacc += __shfl_xor(cntacc, d);
    }
    if (lane == 0) {
        atomicAdd(&nllw[0], nllacc);
        atomicAdd(&nllw[1], cntacc);
    }
    __syncthreads();
    if (t < 512) aggBN[(size_t)blockIdx.x * 512 + t] = bn[t];
    if (t == 0) {
        aggNLL[blockIdx.x * 2 + 0] = nllw[0];
        aggNLL[blockIdx.x * 2 + 1] = nllw[1];
    }
}

// ---------------------------------------------------------------------------
// kernel 2: reduce BN slot partials -> affine hn = h*A + B  (256 blocks x 64)
// ---------------------------------------------------------------------------
__global__ void k_reduce(const float* __restrict__ gamma, const float* __restrict__ beta,
                         const float* __restrict__ aggBN,
                         float* __restrict__ Aarr, float* __restrict__ Barr) {
    int c = blockIdx.x;      // channel
    int l = threadIdx.x;     // 0..63
    float s1 = 0.f, s2 = 0.f;
#pragma unroll
    for (int i = 0; i < 4; ++i) {
        int s = l + i * 64;
        s1 += aggBN[s * 512 + c];
        s2 += aggBN[s * 512 + 256 + c];
    }
#pragma unroll
    for (int d = 1; d < 64; d <<= 1) {
        s1 += __shfl_xor(s1, d);
        s2 += __shfl_xor(s2, d);
    }
    if (l == 0) {
        const float inv = 1.f / (float)NPTS;
        float mu = s1 * inv;
        float var = fmaxf(s2 * inv - mu * mu, 0.f);   // biased var (torch BN)
        float a = gamma[c] * rsqrtf(var + 1e-3f);
        Aarr[c] = a;
        Barr[c] = beta[c] - mu * a;
    }
}

// ---------------------------------------------------------------------------
// kernel 3 (v7, VALU-dot): bias_pred = relu(h*A+B) @ w2 + b2; masked L1+cos.
// Output is only 3 cols -> MFMA is overkill. Reads h2 in producer layout
// (512 B/wave-instr coalesced), 12 per-lane partial dots over the lane's 16
// channels, shfl-reduce over i16. ~50 VGPR -> deep occupancy. No barriers
// until the tiny block reduce.
// ---------------------------------------------------------------------------
__global__ __launch_bounds__(256) void k_loss(
    const u16* __restrict__ h2, const float* __restrict__ Aarr, const float* __restrict__ Barr,
    const float* __restrict__ w2p, const float* __restrict__ b2,
    const float* __restrict__ coord, const float* __restrict__ cent,
    const int* __restrict__ inst, float* __restrict__ aggL)
{
    __shared__ float red[12];

    const int t = threadIdx.x;
    const int lane = t & 63;
    const int wv = t >> 6;
    const int q = lane >> 4;
    const int i16 = lane & 15;
    const int s = blockIdx.x * 4 + wv;            // strip

    float px[4] = {0.f, 0.f, 0.f, 0.f};
    float py[4] = {0.f, 0.f, 0.f, 0.f};
    float pz[4] = {0.f, 0.f, 0.f, 0.f};

#pragma unroll
    for (int ct = 0; ct < 16; ++ct) {
        uint2 d = *(const uint2*)((const char*)h2 + (size_t)s * 8192 + ct * 512 + lane * 8);
        int ch = ct * 16 + i16;
        float A = Aarr[ch], B = Barr[ch];
        float4 w = *(const float4*)(w2p + ch * 4);
        float hv[4] = {bf2f((u16)(d.x & 0xffff)), bf2f((u16)(d.x >> 16)),
                       bf2f((u16)(d.y & 0xffff)), bf2f((u16)(d.y >> 16))};
#pragma unroll
        for (int j = 0; j < 4; ++j) {
            float v = fmaxf(fmaf(hv[j], A, B), 0.f);
            px[j] = fmaf(v, w.x, px[j]);
            py[j] = fmaf(v, w.y, py[j]);
            pz[j] = fmaf(v, w.z, pz[j]);
        }
    }
    // reduce partial dots over i16 (16 channels/lane -> 256)
#pragma unroll
    for (int d = 1; d < 16; d <<= 1) {
#pragma unroll
        for (int j = 0; j < 4; ++j) {
            px[j] += __shfl_xor(px[j], d);
            py[j] += __shfl_xor(py[j], d);
            pz[j] += __shfl_xor(pz[j], d);
        }
    }

    float l1a = 0.f, cosa = 0.f, ma = 0.f;
    if (i16 == 0) {
        float b2x = b2[0], b2y = b2[1], b2z = b2[2];
#pragma unroll
        for (int j = 0; j < 4; ++j) {
            int row = s * 16 + q * 4 + j;
            float bpx = px[j] + b2x, bpy = py[j] + b2y, bpz = pz[j] + b2z;
            const float* cp = coord + (size_t)row * 3;
            const float* ip = cent + (size_t)row * 3;
            float gx = ip[0] - cp[0], gy = ip[1] - cp[1], gz = ip[2] - cp[2];
            float mk = (inst[row] != -1) ? 1.f : 0.f;
            float l1 = fabsf(bpx - gx) + fabsf(bpy - gy) + fabsf(bpz - gz);
            float np = sqrtf(fmaf(bpx, bpx, fmaf(bpy, bpy, bpz * bpz)));
            float ng = sqrtf(fmaf(gx, gx, fmaf(gy, gy, gz * gz)));
            float dp = fmaf(bpx, gx, fmaf(bpy, gy, bpz * gz));
            float cosv = -dp / ((np + 1e-8f) * (ng + 1e-8f));
            l1a += l1 * mk;
            cosa += cosv * mk;
            ma += mk;
        }
    }
    l1a += __shfl_xor(l1a, 16); l1a += __shfl_xor(l1a, 32);
    cosa += __shfl_xor(cosa, 16); cosa += __shfl_xor(cosa, 32);
    ma += __shfl_xor(ma, 16); ma += __shfl_xor(ma, 32);
    if (lane == 0) { red[wv] = l1a; red[4 + wv] = cosa; red[8 + wv] = ma; }
    __syncthreads();
    if (t == 0) {
        int slot = blockIdx.x & (LSLOT - 1);
        atomicAdd(aggL + slot * 4 + 0, red[0] + red[1] + red[2] + red[3]);
        atomicAdd(aggL + slot * 4 + 1, red[4] + red[5] + red[6] + red[7]);
        atomicAdd(aggL + slot * 4 + 2, red[8] + red[9] + red[10] + red[11]);
    }
}

// ---------------------------------------------------------------------------
// kernel 4: final scalars — reduce NLL + loss slots, emit 4 outputs (1 wave)
// ---------------------------------------------------------------------------
__global__ void k_final(const float* __restrict__ aggNLL, const float* __restrict__ aggL,
                        float* __restrict__ out) {
    int lane = threadIdx.x;   // 0..63
    float nll = 0.f, cnt = 0.f, l1 = 0.f, cs = 0.f, mk = 0.f;
#pragma unroll
    for (int i = 0; i < 4; ++i) {
        int s = lane + i * 64;
        nll += aggNLL[s * 2 + 0];
        cnt += aggNLL[s * 2 + 1];
        l1 += aggL[s * 4 + 0];
        cs += aggL[s * 4 + 1];
        mk += aggL[s * 4 + 2];
    }
#pragma unroll
    for (int d = 1; d < 64; d <<= 1) {
        nll += __shfl_xor(nll, d);
        cnt += __shfl_xor(cnt, d);
        l1 += __shfl_xor(l1, d);
        cs += __shfl_xor(cs, d);
        mk += __shfl_xor(mk, d);
    }
    if (lane == 0) {
        float seg = nll / (cnt + 1e-8f);
        float l1l = l1 / (mk + 1e-8f);
        float csl = cs / (mk + 1e-8f);
        out[0] = seg + l1l + csl;
        out[1] = seg;
        out[2] = l1l;
        out[3] = csl;
    }
}

extern "C" void kernel_launch(void* const* d_in, const int* in_sizes, int n_in,
                              void* d_out, int out_size, void* d_ws, size_t ws_size,
                              hipStream_t stream) {
    const float* feat   = (const float*)d_in[0];
    const float* coord  = (const float*)d_in[1];
    const float* cent   = (const float*)d_in[2];
    const int* segment  = (const int*)d_in[3];
    const int* inst     = (const int*)d_in[4];
    const float* w1     = (const float*)d_in[5];
    const float* b1     = (const float*)d_in[6];
    const float* gamma  = (const float*)d_in[7];
    const float* beta   = (const float*)d_in[8];
    const float* w2     = (const float*)d_in[9];
    const float* b2     = (const float*)d_in[10];
    const float* wsm    = (const float*)d_in[11];
    const float* bs     = (const float*)d_in[12];
    float* out = (float*)d_out;

    char* wsb = (char*)d_ws;
    u16* h2      = (u16*)wsb;
    u16* Wt3     = (u16*)(wsb + OFF_WT);
    float* w2p   = (float*)(wsb + OFF_W2P);
    float* aggBN = (float*)(wsb + OFF_AGGBN);
    float* aggNL = (float*)(wsb + OFF_AGGNL);
    float* aggL  = (float*)(wsb + OFF_AGGL);
    float* Aarr  = (float*)(wsb + OFF_AB);
    float* Barr  = Aarr + 256;

    if (ws_size < WS_NEED)
        fprintf(stderr, "kernel_launch: ws_size=%zu < needed %zu — WILL CORRUPT\n",
                ws_size, (size_t)WS_NEED);

    hipMemsetAsync(wsb + MEMSET_OFF, 0, MEMSET_LEN, stream);
    k_prep<<<256, 288, 0, stream>>>(w1, wsm, w2, Wt3, w2p);
    k_fused<<<256, 1024, 0, stream>>>(feat, b1, bs, segment, Wt3, h2, aggBN, aggNL);
    k_reduce<<<256, 64, 0, stream>>>(gamma, beta, aggBN, Aarr, Barr);
    k_loss<<<4096, 256, 0, stream>>>(h2, Aarr, Barr, w2p, b2, coord, cent, inst, aggL);
    k_final<<<1, 64, 0, stream>>>(aggNL, aggL, out);
}